// Round 6
// baseline (131.784 us; speedup 1.0000x reference)
//
#include <hip/hip_runtime.h>
#include <cstdint>
#include <cstddef>

#define NB 8
#define NG 64
#define NP 50000
#define NBLK 98                 // ceil((NP/2)/256)
#define NPART (NBLK * 4)        // 392 wave-partials per (b,g) row

__device__ __forceinline__ void opaque(float& x) { asm volatile("" : "+v"(x)); }
__device__ __forceinline__ unsigned long long umax64(unsigned long long a, unsigned long long b) {
    return a > b ? a : b;
}

// Main kernel: streaming iou/pos/neg + per-wave argmax partials (post-loop butterflies).
template<bool WRITE_KEYS>
__global__ __launch_bounds__(256) void iou_main(
    const float* __restrict__ pred,
    const float* __restrict__ gt,
    float* __restrict__ out_iou,
    float* __restrict__ out_pos,
    float* __restrict__ out_neg,
    unsigned long long* __restrict__ keys)
{
    __shared__ float s_gx0[NG], s_gy0[NG], s_gx1[NG], s_gy1[NG], s_ga[NG];
    const int b = blockIdx.y;
    const int tid = threadIdx.x;

    if (tid < NG) {
        const float4 gb = reinterpret_cast<const float4*>(gt)[b * NG + tid];
        float hw = 0.5f * gb.z, hh = 0.5f * gb.w;   // exact, FMA-safe
        float x0 = gb.x - hw, y0 = gb.y - hh;
        float x1 = gb.x + hw, y1 = gb.y + hh;
        float ga = (x1 - x0) * (y1 - y0);
        opaque(ga);                                  // block FMA contraction into sums
        s_gx0[tid] = x0; s_gy0[tid] = y0;
        s_gx1[tid] = x1; s_gy1[tid] = y1;
        s_ga[tid]  = ga;
    }
    __syncthreads();

    const int p = 2 * (blockIdx.x * 256 + tid);
    const bool active = p < NP;                      // p even, NP even -> p and p+1 both valid
    const int pc = active ? p : 0;

    const float4 pb0 = reinterpret_cast<const float4*>(pred)[(size_t)b * NP + pc];
    const float4 pb1 = reinterpret_cast<const float4*>(pred)[(size_t)b * NP + pc + 1];

    float hw0 = 0.5f * pb0.z, hh0 = 0.5f * pb0.w;
    const float ax0 = pb0.x - hw0, ay0 = pb0.y - hh0;
    const float ax1 = pb0.x + hw0, ay1 = pb0.y + hh0;
    float pa0 = (ax1 - ax0) * (ay1 - ay0);
    opaque(pa0);

    float hw1 = 0.5f * pb1.z, hh1 = 0.5f * pb1.w;
    const float bx0 = pb1.x - hw1, by0 = pb1.y - hh1;
    const float bx1 = pb1.x + hw1, by1 = pb1.y + hh1;
    float pa1 = (bx1 - bx0) * (by1 - by0);
    opaque(pa1);

    float maxv0 = 0.0f, maxv1 = 0.0f;
    const size_t base = (size_t)b * NG * NP + (size_t)pc;

    float va[NG];                                    // statically indexed (full unroll)
    unsigned int cm0 = 0, cm1 = 0;                   // per-g "second pred wins" bits

    #pragma unroll
    for (int g = 0; g < NG; ++g) {
        const float gx0 = s_gx0[g], gy0 = s_gy0[g];
        const float gx1 = s_gx1[g], gy1 = s_gy1[g];
        const float ga  = s_ga[g];

        float w0 = fmaxf(fminf(gx1, ax1) - fmaxf(gx0, ax0), 0.0f);
        float h0 = fmaxf(fminf(gy1, ay1) - fmaxf(gy0, ay0), 0.0f);
        float inter0 = w0 * h0;
        opaque(inter0);                              // numpy op order: (ga+pa)-inter
        float iou0 = inter0 / ((ga + pa0) - inter0); // IEEE div

        float w1 = fmaxf(fminf(gx1, bx1) - fmaxf(gx0, bx0), 0.0f);
        float h1 = fmaxf(fminf(gy1, by1) - fmaxf(gy0, by0), 0.0f);
        float inter1 = w1 * h1;
        opaque(inter1);
        float iou1 = inter1 / ((ga + pa1) - inter1);

        if (WRITE_KEYS) {
            va[g] = active ? fmaxf(iou0, iou1) : -1.0f;
            if (iou1 > iou0) {                       // tie -> first pred (p)
                if (g < 32) cm0 |= 1u << g; else cm1 |= 1u << (g - 32);
            }
        }

        if (active) {
            float2 vi; vi.x = iou0; vi.y = iou1;
            *reinterpret_cast<float2*>(out_iou + base + (size_t)g * NP) = vi;
            float2 vp; vp.x = (iou0 > 0.7f) ? 1.0f : 0.0f;
                       vp.y = (iou1 > 0.7f) ? 1.0f : 0.0f;
            *reinterpret_cast<float2*>(out_pos + base + (size_t)g * NP) = vp;
            maxv0 = fmaxf(maxv0, iou0);
            maxv1 = fmaxf(maxv1, iou1);
        }
    }

    if (active) {
        float2 vn; vn.x = (maxv0 < 0.3f) ? 1.0f : 0.0f;
                   vn.y = (maxv1 < 0.3f) ? 1.0f : 0.0f;
        *reinterpret_cast<float2*>(out_neg + (size_t)b * NP + p) = vn;
    }

    if (WRITE_KEYS) {
        const int lane = tid & 63;
        const int wv = tid >> 6;
        const unsigned int base_p = (unsigned int)(2 * (blockIdx.x * 256 + (tid & ~63)));
        unsigned long long mykey = 0;

        #pragma unroll
        for (int g = 0; g < NG; ++g) {
            float r = va[g];
            float wmax = r;
            #pragma unroll
            for (int s = 1; s < 64; s <<= 1)
                wmax = fmaxf(wmax, __shfl_xor(wmax, s, 64));
            unsigned long long key = 0;
            if (wmax >= 0.0f) {                      // wave-uniform; false only if all lanes inactive
                unsigned long long mwin = __ballot(r == wmax);
                unsigned long long cb   = __ballot((((g < 32) ? cm0 : cm1) >> (g & 31)) & 1u);
                int wl = __ffsll(mwin) - 1;          // lowest lane == lowest p (first occurrence)
                unsigned int widx = base_p + 2u * (unsigned)wl + (unsigned)((cb >> wl) & 1ull);
                key = ((unsigned long long)__float_as_uint(wmax) << 32) |
                      (unsigned long long)(0xFFFFFFFFu - widx);
            }
            if (lane == g) mykey = key;              // lane g carries row (b,g)'s partial
        }
        // layout: keys[(b*NG + g) * NPART + (blk*4 + wave)] -> coalesced reads in pos_fix_keys
        keys[((size_t)b * NG + (size_t)lane) * NPART + (size_t)(blockIdx.x * 4 + wv)] = mykey;
    }
}

// Fused path: reduce 392 wave partials per (b,g) row, set argmax bit.
__global__ __launch_bounds__(256) void pos_fix_keys(
    const unsigned long long* __restrict__ keys,
    float* __restrict__ out_pos)
{
    const int row = blockIdx.x;                      // b*NG + g
    const int t = threadIdx.x;
    const unsigned long long* rk = keys + (size_t)row * NPART;

    unsigned long long k = 0;
    if (t < NPART)       k = rk[t];
    if (t + 256 < NPART) k = umax64(k, rk[t + 256]);

    #pragma unroll
    for (int s = 1; s < 64; s <<= 1)
        k = umax64(k, __shfl_xor(k, s, 64));

    __shared__ unsigned long long sk[4];
    if ((t & 63) == 0) sk[t >> 6] = k;
    __syncthreads();

    if (t == 0) {
        k = umax64(umax64(sk[0], sk[1]), umax64(sk[2], sk[3]));
        unsigned int idx = 0xFFFFFFFFu - (unsigned int)(k & 0xFFFFFFFFull);
        if (idx < NP) out_pos[(size_t)row * NP + idx] = 1.0f;
    }
}

// Fallback path (ws too small): re-scan the iou row for argmax.
__global__ __launch_bounds__(256) void argmax_scan(
    const float* __restrict__ out_iou,
    float* __restrict__ out_pos)
{
    const int row = blockIdx.x;
    const float4* r4 = reinterpret_cast<const float4*>(out_iou + (size_t)row * NP);

    float bv = -1.0f;
    int   bi = 0x7fffffff;
    for (int c = threadIdx.x; c < NP / 4; c += 256) {
        float4 v = r4[c];
        int p = 4 * c;
        if (v.x > bv) { bv = v.x; bi = p; }
        if (v.y > bv) { bv = v.y; bi = p + 1; }
        if (v.z > bv) { bv = v.z; bi = p + 2; }
        if (v.w > bv) { bv = v.w; bi = p + 3; }
    }
    #pragma unroll
    for (int s = 1; s < 64; s <<= 1) {
        float ov = __shfl_xor(bv, s, 64);
        int   oi = __shfl_xor(bi, s, 64);
        if (ov > bv || (ov == bv && oi < bi)) { bv = ov; bi = oi; }
    }
    __shared__ float sv[4];
    __shared__ int   si[4];
    const int wid = threadIdx.x >> 6;
    if ((threadIdx.x & 63) == 0) { sv[wid] = bv; si[wid] = bi; }
    __syncthreads();
    if (threadIdx.x == 0) {
        for (int w = 1; w < 4; ++w)
            if (sv[w] > bv || (sv[w] == bv && si[w] < bi)) { bv = sv[w]; bi = si[w]; }
        out_pos[(size_t)row * NP + bi] = 1.0f;
    }
}

extern "C" void kernel_launch(void* const* d_in, const int* in_sizes, int n_in,
                              void* d_out, int out_size, void* d_ws, size_t ws_size,
                              hipStream_t stream) {
    const float* pred = (const float*)d_in[0];
    const float* gt   = (const float*)d_in[1];
    float* out_iou = (float*)d_out;
    float* out_pos = out_iou + (size_t)NB * NG * NP;
    float* out_neg = out_pos + (size_t)NB * NG * NP;

    const size_t keys_bytes = (size_t)NB * NG * NPART * sizeof(unsigned long long);
    dim3 grid1(NBLK, NB);

    if (ws_size >= keys_bytes) {
        unsigned long long* keys = (unsigned long long*)d_ws;
        iou_main<true><<<grid1, dim3(256), 0, stream>>>(pred, gt, out_iou, out_pos, out_neg, keys);
        pos_fix_keys<<<dim3(NB * NG), dim3(256), 0, stream>>>(keys, out_pos);
    } else {
        iou_main<false><<<grid1, dim3(256), 0, stream>>>(pred, gt, out_iou, out_pos, out_neg, nullptr);
        argmax_scan<<<dim3(NB * NG), dim3(256), 0, stream>>>(out_iou, out_pos);
    }
}

// Round 7
// 80.976 us; speedup vs baseline: 1.6275x; 1.6275x over previous
//
#include <hip/hip_runtime.h>
#include <cstdint>
#include <cstddef>

#define NB 8
#define NG 64
#define NP 50000
#define NBLK 98                 // ceil((NP/2)/256)
#define NPART (NBLK * 4)        // 392 wave-partials per (b,g) row
#define CHUNK 8                 // g's per reduction chunk (keeps VGPRs flat)

__device__ __forceinline__ void opaque(float& x) { asm volatile("" : "+v"(x)); }
__device__ __forceinline__ unsigned long long umax64(unsigned long long a, unsigned long long b) {
    return a > b ? a : b;
}

// Main kernel: streaming iou/pos/neg + chunked per-wave argmax partials.
// keys layout: keys[(b*NPART + part)*NG + g]  (coalesced 64B writes per chunk per wave)
template<bool WRITE_KEYS>
__global__ __launch_bounds__(256) void iou_main(
    const float* __restrict__ pred,
    const float* __restrict__ gt,
    float* __restrict__ out_iou,
    float* __restrict__ out_pos,
    float* __restrict__ out_neg,
    unsigned long long* __restrict__ keys)
{
    __shared__ float s_gx0[NG], s_gy0[NG], s_gx1[NG], s_gy1[NG], s_ga[NG];
    const int b = blockIdx.y;
    const int tid = threadIdx.x;

    if (tid < NG) {
        const float4 gb = reinterpret_cast<const float4*>(gt)[b * NG + tid];
        float hw = 0.5f * gb.z, hh = 0.5f * gb.w;   // exact, FMA-safe
        float x0 = gb.x - hw, y0 = gb.y - hh;
        float x1 = gb.x + hw, y1 = gb.y + hh;
        float ga = (x1 - x0) * (y1 - y0);
        opaque(ga);                                  // block FMA contraction into sums
        s_gx0[tid] = x0; s_gy0[tid] = y0;
        s_gx1[tid] = x1; s_gy1[tid] = y1;
        s_ga[tid]  = ga;
    }
    __syncthreads();

    const int p = 2 * (blockIdx.x * 256 + tid);
    const bool active = p < NP;                      // p even, NP even -> p,p+1 both valid
    const int pc = active ? p : 0;

    const float4 pb0 = reinterpret_cast<const float4*>(pred)[(size_t)b * NP + pc];
    const float4 pb1 = reinterpret_cast<const float4*>(pred)[(size_t)b * NP + pc + 1];

    float hw0 = 0.5f * pb0.z, hh0 = 0.5f * pb0.w;
    const float ax0 = pb0.x - hw0, ay0 = pb0.y - hh0;
    const float ax1 = pb0.x + hw0, ay1 = pb0.y + hh0;
    float pa0 = (ax1 - ax0) * (ay1 - ay0);
    opaque(pa0);

    float hw1 = 0.5f * pb1.z, hh1 = 0.5f * pb1.w;
    const float bx0 = pb1.x - hw1, by0 = pb1.y - hh1;
    const float bx1 = pb1.x + hw1, by1 = pb1.y + hh1;
    float pa1 = (bx1 - bx0) * (by1 - by0);
    opaque(pa1);

    float maxv0 = 0.0f, maxv1 = 0.0f;
    const size_t base = (size_t)b * NG * NP + (size_t)pc;

    const int lane = tid & 63;
    const int wv = tid >> 6;
    const unsigned int base_p = (unsigned int)(2 * (blockIdx.x * 256 + (tid & ~63)));
    const size_t wave_slab = ((size_t)b * NPART + (size_t)(blockIdx.x * 4 + wv)) * NG;

    #pragma unroll 1                                 // keep VGPR lifetime per-chunk
    for (int c = 0; c < NG / CHUNK; ++c) {
        float va[CHUNK];                             // statically indexed after unroll
        unsigned int cm = 0;                         // per-j "second pred wins" bits

        #pragma unroll
        for (int j = 0; j < CHUNK; ++j) {
            const int g = c * CHUNK + j;
            const float gx0 = s_gx0[g], gy0 = s_gy0[g];
            const float gx1 = s_gx1[g], gy1 = s_gy1[g];
            const float ga  = s_ga[g];

            float w0 = fmaxf(fminf(gx1, ax1) - fmaxf(gx0, ax0), 0.0f);
            float h0 = fmaxf(fminf(gy1, ay1) - fmaxf(gy0, ay0), 0.0f);
            float inter0 = w0 * h0;
            opaque(inter0);                          // numpy op order: (ga+pa)-inter
            float iou0 = inter0 / ((ga + pa0) - inter0); // IEEE div

            float w1 = fmaxf(fminf(gx1, bx1) - fmaxf(gx0, bx0), 0.0f);
            float h1 = fmaxf(fminf(gy1, by1) - fmaxf(gy0, by0), 0.0f);
            float inter1 = w1 * h1;
            opaque(inter1);
            float iou1 = inter1 / ((ga + pa1) - inter1);

            if (WRITE_KEYS) {
                va[j] = active ? fmaxf(iou0, iou1) : -1.0f;
                if (iou1 > iou0) cm |= 1u << j;      // tie -> first pred (p)
            }

            if (active) {
                float2 vi; vi.x = iou0; vi.y = iou1;
                *reinterpret_cast<float2*>(out_iou + base + (size_t)g * NP) = vi;
                float2 vp; vp.x = (iou0 > 0.7f) ? 1.0f : 0.0f;
                           vp.y = (iou1 > 0.7f) ? 1.0f : 0.0f;
                *reinterpret_cast<float2*>(out_pos + base + (size_t)g * NP) = vp;
                maxv0 = fmaxf(maxv0, iou0);
                maxv1 = fmaxf(maxv1, iou1);
            }
        }

        if (WRITE_KEYS) {
            unsigned long long myk = 0;
            #pragma unroll
            for (int j = 0; j < CHUNK; ++j) {        // 8 independent butterflies (ILP)
                float r = va[j];
                float wmax = r;
                #pragma unroll
                for (int s = 1; s < 64; s <<= 1)
                    wmax = fmaxf(wmax, __shfl_xor(wmax, s, 64));
                unsigned long long key = 0;
                if (wmax >= 0.0f) {                  // wave-uniform
                    unsigned long long mwin = __ballot(r == wmax);
                    unsigned long long cb   = __ballot((cm >> j) & 1u);
                    int wl = __ffsll(mwin) - 1;      // lowest lane == lowest p
                    unsigned int widx = base_p + 2u * (unsigned)wl + (unsigned)((cb >> wl) & 1ull);
                    key = ((unsigned long long)__float_as_uint(wmax) << 32) |
                          (unsigned long long)(0xFFFFFFFFu - widx);
                }
                if (lane == j) myk = key;            // lane j carries g=c*8+j's partial
            }
            if (lane < CHUNK)                        // 64B coalesced store
                keys[wave_slab + (size_t)(c * CHUNK + lane)] = myk;
        }
    }

    if (active) {
        float2 vn; vn.x = (maxv0 < 0.3f) ? 1.0f : 0.0f;
                   vn.y = (maxv1 < 0.3f) ? 1.0f : 0.0f;
        *reinterpret_cast<float2*>(out_neg + (size_t)b * NP + p) = vn;
    }
}

// Reduce 392 partials per (b,g) row. One block per b; thread t: g=t&63, quarter=t>>6.
__global__ __launch_bounds__(256) void pos_fix_keys(
    const unsigned long long* __restrict__ keys,
    float* __restrict__ out_pos)
{
    const int b = blockIdx.x;
    const int t = threadIdx.x;
    const int g = t & 63;
    const int q = t >> 6;

    unsigned long long k = 0;
    for (int part = q; part < NPART; part += 4)      // lanes read consecutive g: coalesced
        k = umax64(k, keys[((size_t)b * NPART + part) * NG + g]);

    __shared__ unsigned long long sk[4][NG];
    sk[q][g] = k;
    __syncthreads();

    if (t < NG) {
        k = umax64(umax64(sk[0][t], sk[1][t]), umax64(sk[2][t], sk[3][t]));
        unsigned int idx = 0xFFFFFFFFu - (unsigned int)(k & 0xFFFFFFFFull);
        if (idx < NP)
            out_pos[((size_t)b * NG + t) * NP + idx] = 1.0f;
    }
}

// Fallback path (ws too small): re-scan the iou row for argmax.
__global__ __launch_bounds__(256) void argmax_scan(
    const float* __restrict__ out_iou,
    float* __restrict__ out_pos)
{
    const int row = blockIdx.x;
    const float4* r4 = reinterpret_cast<const float4*>(out_iou + (size_t)row * NP);

    float bv = -1.0f;
    int   bi = 0x7fffffff;
    for (int c = threadIdx.x; c < NP / 4; c += 256) {
        float4 v = r4[c];
        int p = 4 * c;
        if (v.x > bv) { bv = v.x; bi = p; }
        if (v.y > bv) { bv = v.y; bi = p + 1; }
        if (v.z > bv) { bv = v.z; bi = p + 2; }
        if (v.w > bv) { bv = v.w; bi = p + 3; }
    }
    #pragma unroll
    for (int s = 1; s < 64; s <<= 1) {
        float ov = __shfl_xor(bv, s, 64);
        int   oi = __shfl_xor(bi, s, 64);
        if (ov > bv || (ov == bv && oi < bi)) { bv = ov; bi = oi; }
    }
    __shared__ float sv[4];
    __shared__ int   si[4];
    const int wid = threadIdx.x >> 6;
    if ((threadIdx.x & 63) == 0) { sv[wid] = bv; si[wid] = bi; }
    __syncthreads();
    if (threadIdx.x == 0) {
        for (int w = 1; w < 4; ++w)
            if (sv[w] > bv || (sv[w] == bv && si[w] < bi)) { bv = sv[w]; bi = si[w]; }
        out_pos[(size_t)row * NP + bi] = 1.0f;
    }
}

extern "C" void kernel_launch(void* const* d_in, const int* in_sizes, int n_in,
                              void* d_out, int out_size, void* d_ws, size_t ws_size,
                              hipStream_t stream) {
    const float* pred = (const float*)d_in[0];
    const float* gt   = (const float*)d_in[1];
    float* out_iou = (float*)d_out;
    float* out_pos = out_iou + (size_t)NB * NG * NP;
    float* out_neg = out_pos + (size_t)NB * NG * NP;

    const size_t keys_bytes = (size_t)NB * NPART * NG * sizeof(unsigned long long);
    dim3 grid1(NBLK, NB);

    if (ws_size >= keys_bytes) {
        unsigned long long* keys = (unsigned long long*)d_ws;
        iou_main<true><<<grid1, dim3(256), 0, stream>>>(pred, gt, out_iou, out_pos, out_neg, keys);
        pos_fix_keys<<<dim3(NB), dim3(256), 0, stream>>>(keys, out_pos);
    } else {
        iou_main<false><<<grid1, dim3(256), 0, stream>>>(pred, gt, out_iou, out_pos, out_neg, nullptr);
        argmax_scan<<<dim3(NB * NG), dim3(256), 0, stream>>>(out_iou, out_pos);
    }
}

// Round 8
// 71.795 us; speedup vs baseline: 1.8356x; 1.1279x over previous
//
#include <hip/hip_runtime.h>
#include <cstdint>
#include <cstddef>

#define NB 8
#define NG 64
#define NP 50000
#define NBLK 98                 // ceil((NP/2)/256) for the streaming kernel
#define PCH 6250                // NP/8: p-chunk per argmax block
#define NPCH 8                  // p-chunks per row

__device__ __forceinline__ void opaque(float& x) { asm volatile("" : "+v"(x)); }
__device__ __forceinline__ unsigned long long umax64(unsigned long long a, unsigned long long b) {
    return a > b ? a : b;
}

// ---------------------------------------------------------------------------
// Kernel B: row-oriented argmax partials, RECOMPUTING iou from pred (6.4 MB read).
// Grid (NPCH, 8 g-groups, NB). Each block: 8 g-rows x 6250 preds.
// part[row = b*NG+g][chunk] = (iou_bits<<32) | (0xFFFFFFFF - p)   (u64 max == argmax, first-occurrence)
__global__ __launch_bounds__(256) void argmax_part(
    const float* __restrict__ pred,
    const float* __restrict__ gt,
    unsigned long long* __restrict__ part)
{
    __shared__ float s_gx0[8], s_gy0[8], s_gx1[8], s_gy1[8], s_ga[8];
    const int b  = blockIdx.z;
    const int gg = blockIdx.y;
    const int p0 = blockIdx.x * PCH;
    const int tid = threadIdx.x;

    if (tid < 8) {
        const float4 gb = reinterpret_cast<const float4*>(gt)[b * NG + gg * 8 + tid];
        float hw = 0.5f * gb.z, hh = 0.5f * gb.w;   // exact, FMA-safe
        float x0 = gb.x - hw, y0 = gb.y - hh;
        float x1 = gb.x + hw, y1 = gb.y + hh;
        float ga = (x1 - x0) * (y1 - y0);
        opaque(ga);
        s_gx0[tid] = x0; s_gy0[tid] = y0;
        s_gx1[tid] = x1; s_gy1[tid] = y1;
        s_ga[tid]  = ga;
    }
    __syncthreads();

    unsigned long long k0 = 0, k1 = 0, k2 = 0, k3 = 0, k4 = 0, k5 = 0, k6 = 0, k7 = 0;

    for (int i = tid; i < PCH; i += 256) {
        const int p = p0 + i;
        const float4 pb = reinterpret_cast<const float4*>(pred)[(size_t)b * NP + p];
        float hw = 0.5f * pb.z, hh = 0.5f * pb.w;
        const float px0 = pb.x - hw, py0 = pb.y - hh;
        const float px1 = pb.x + hw, py1 = pb.y + hh;
        float pa = (px1 - px0) * (py1 - py0);
        opaque(pa);

        const unsigned int ip = 0xFFFFFFFFu - (unsigned int)p;
        unsigned long long* ks[8] = { &k0,&k1,&k2,&k3,&k4,&k5,&k6,&k7 };
        #pragma unroll
        for (int j = 0; j < 8; ++j) {
            // identical expression structure to the streaming kernel -> bitwise-equal iou
            float w = fmaxf(fminf(s_gx1[j], px1) - fmaxf(s_gx0[j], px0), 0.0f);
            float h = fmaxf(fminf(s_gy1[j], py1) - fmaxf(s_gy0[j], py0), 0.0f);
            float inter = w * h;
            opaque(inter);                           // numpy op order: (ga+pa)-inter
            float iou = inter / ((s_ga[j] + pa) - inter);  // IEEE div
            unsigned long long key =
                ((unsigned long long)__float_as_uint(iou) << 32) | (unsigned long long)ip;
            *ks[j] = umax64(*ks[j], key);
        }
    }

    // block reduction: butterfly within wave, LDS across the 4 waves
    __shared__ unsigned long long s_part[8][4];
    const int lane = tid & 63;
    const int wv = tid >> 6;
    unsigned long long ka[8] = { k0,k1,k2,k3,k4,k5,k6,k7 };
    #pragma unroll
    for (int j = 0; j < 8; ++j) {
        unsigned long long k = ka[j];
        #pragma unroll
        for (int s = 1; s < 64; s <<= 1)
            k = umax64(k, __shfl_xor(k, s, 64));
        if (lane == 0) s_part[j][wv] = k;
    }
    __syncthreads();

    if (tid < 8) {
        unsigned long long r = umax64(umax64(s_part[tid][0], s_part[tid][1]),
                                      umax64(s_part[tid][2], s_part[tid][3]));
        part[((size_t)b * NG + (size_t)(gg * 8 + tid)) * NPCH + blockIdx.x] = r;
    }
}

// ---------------------------------------------------------------------------
// Kernel A: pure streaming — iou, pos (threshold | onehot), neg. One pass.
template<bool USE_AM>
__global__ __launch_bounds__(256) void iou_main(
    const float* __restrict__ pred,
    const float* __restrict__ gt,
    float* __restrict__ out_iou,
    float* __restrict__ out_pos,
    float* __restrict__ out_neg,
    const unsigned long long* __restrict__ part)
{
    __shared__ float s_gx0[NG], s_gy0[NG], s_gx1[NG], s_gy1[NG], s_ga[NG];
    __shared__ unsigned int s_am[NG];
    const int b = blockIdx.y;
    const int tid = threadIdx.x;

    if (tid < NG) {
        const float4 gb = reinterpret_cast<const float4*>(gt)[b * NG + tid];
        float hw = 0.5f * gb.z, hh = 0.5f * gb.w;   // exact, FMA-safe
        float x0 = gb.x - hw, y0 = gb.y - hh;
        float x1 = gb.x + hw, y1 = gb.y + hh;
        float ga = (x1 - x0) * (y1 - y0);
        opaque(ga);                                  // block FMA contraction into sums
        s_gx0[tid] = x0; s_gy0[tid] = y0;
        s_gx1[tid] = x1; s_gy1[tid] = y1;
        s_ga[tid]  = ga;
        if (USE_AM) {
            const unsigned long long* pr = part + ((size_t)b * NG + tid) * NPCH;
            unsigned long long r = pr[0];
            #pragma unroll
            for (int c = 1; c < NPCH; ++c) r = umax64(r, pr[c]);
            s_am[tid] = 0xFFFFFFFFu - (unsigned int)(r & 0xFFFFFFFFull);
        }
    }
    __syncthreads();

    const int p = 2 * (blockIdx.x * 256 + tid);
    if (p >= NP) return;                             // no barriers after this

    const float4 pb0 = reinterpret_cast<const float4*>(pred)[(size_t)b * NP + p];
    const float4 pb1 = reinterpret_cast<const float4*>(pred)[(size_t)b * NP + p + 1];

    float hw0 = 0.5f * pb0.z, hh0 = 0.5f * pb0.w;
    const float ax0 = pb0.x - hw0, ay0 = pb0.y - hh0;
    const float ax1 = pb0.x + hw0, ay1 = pb0.y + hh0;
    float pa0 = (ax1 - ax0) * (ay1 - ay0);
    opaque(pa0);

    float hw1 = 0.5f * pb1.z, hh1 = 0.5f * pb1.w;
    const float bx0 = pb1.x - hw1, by0 = pb1.y - hh1;
    const float bx1 = pb1.x + hw1, by1 = pb1.y + hh1;
    float pa1 = (bx1 - bx0) * (by1 - by0);
    opaque(pa1);

    float maxv0 = 0.0f, maxv1 = 0.0f;
    const size_t base = (size_t)b * NG * NP + (size_t)p;
    const unsigned int up = (unsigned int)p;

    #pragma unroll 8
    for (int g = 0; g < NG; ++g) {
        const float gx0 = s_gx0[g], gy0 = s_gy0[g];
        const float gx1 = s_gx1[g], gy1 = s_gy1[g];
        const float ga  = s_ga[g];

        float w0 = fmaxf(fminf(gx1, ax1) - fmaxf(gx0, ax0), 0.0f);
        float h0 = fmaxf(fminf(gy1, ay1) - fmaxf(gy0, ay0), 0.0f);
        float inter0 = w0 * h0;
        opaque(inter0);                              // numpy op order: (ga+pa)-inter
        float iou0 = inter0 / ((ga + pa0) - inter0); // IEEE div

        float w1 = fmaxf(fminf(gx1, bx1) - fmaxf(gx0, bx0), 0.0f);
        float h1 = fmaxf(fminf(gy1, by1) - fmaxf(gy0, by0), 0.0f);
        float inter1 = w1 * h1;
        opaque(inter1);
        float iou1 = inter1 / ((ga + pa1) - inter1);

        float2 vi; vi.x = iou0; vi.y = iou1;
        *reinterpret_cast<float2*>(out_iou + base + (size_t)g * NP) = vi;

        float2 vp;
        if (USE_AM) {
            const unsigned int am = s_am[g];
            vp.x = (iou0 > 0.7f || am == up)      ? 1.0f : 0.0f;
            vp.y = (iou1 > 0.7f || am == up + 1u) ? 1.0f : 0.0f;
        } else {
            vp.x = (iou0 > 0.7f) ? 1.0f : 0.0f;
            vp.y = (iou1 > 0.7f) ? 1.0f : 0.0f;
        }
        *reinterpret_cast<float2*>(out_pos + base + (size_t)g * NP) = vp;

        maxv0 = fmaxf(maxv0, iou0);
        maxv1 = fmaxf(maxv1, iou1);
    }

    float2 vn; vn.x = (maxv0 < 0.3f) ? 1.0f : 0.0f;
               vn.y = (maxv1 < 0.3f) ? 1.0f : 0.0f;
    *reinterpret_cast<float2*>(out_neg + (size_t)b * NP + p) = vn;
}

// Fallback (ws too small): re-scan the iou row for argmax.
__global__ __launch_bounds__(256) void argmax_scan(
    const float* __restrict__ out_iou,
    float* __restrict__ out_pos)
{
    const int row = blockIdx.x;
    const float4* r4 = reinterpret_cast<const float4*>(out_iou + (size_t)row * NP);

    float bv = -1.0f;
    int   bi = 0x7fffffff;
    for (int c = threadIdx.x; c < NP / 4; c += 256) {
        float4 v = r4[c];
        int p = 4 * c;
        if (v.x > bv) { bv = v.x; bi = p; }
        if (v.y > bv) { bv = v.y; bi = p + 1; }
        if (v.z > bv) { bv = v.z; bi = p + 2; }
        if (v.w > bv) { bv = v.w; bi = p + 3; }
    }
    #pragma unroll
    for (int s = 1; s < 64; s <<= 1) {
        float ov = __shfl_xor(bv, s, 64);
        int   oi = __shfl_xor(bi, s, 64);
        if (ov > bv || (ov == bv && oi < bi)) { bv = ov; bi = oi; }
    }
    __shared__ float sv[4];
    __shared__ int   si[4];
    const int wid = threadIdx.x >> 6;
    if ((threadIdx.x & 63) == 0) { sv[wid] = bv; si[wid] = bi; }
    __syncthreads();
    if (threadIdx.x == 0) {
        for (int w = 1; w < 4; ++w)
            if (sv[w] > bv || (sv[w] == bv && si[w] < bi)) { bv = sv[w]; bi = si[w]; }
        out_pos[(size_t)row * NP + bi] = 1.0f;
    }
}

extern "C" void kernel_launch(void* const* d_in, const int* in_sizes, int n_in,
                              void* d_out, int out_size, void* d_ws, size_t ws_size,
                              hipStream_t stream) {
    const float* pred = (const float*)d_in[0];
    const float* gt   = (const float*)d_in[1];
    float* out_iou = (float*)d_out;
    float* out_pos = out_iou + (size_t)NB * NG * NP;
    float* out_neg = out_pos + (size_t)NB * NG * NP;

    const size_t part_bytes = (size_t)NB * NG * NPCH * sizeof(unsigned long long); // 32 KB
    dim3 gridA(NBLK, NB);

    if (ws_size >= part_bytes) {
        unsigned long long* part = (unsigned long long*)d_ws;
        argmax_part<<<dim3(NPCH, NG / 8, NB), dim3(256), 0, stream>>>(pred, gt, part);
        iou_main<true><<<gridA, dim3(256), 0, stream>>>(pred, gt, out_iou, out_pos, out_neg, part);
    } else {
        iou_main<false><<<gridA, dim3(256), 0, stream>>>(pred, gt, out_iou, out_pos, out_neg, nullptr);
        argmax_scan<<<dim3(NB * NG), dim3(256), 0, stream>>>(out_iou, out_pos);
    }
}

// Round 9
// 65.557 us; speedup vs baseline: 2.0102x; 1.0951x over previous
//
#include <hip/hip_runtime.h>
#include <cstdint>
#include <cstddef>

#define NB 8
#define NG 64
#define NP 50000
#define NBLK 98                 // ceil((NP/2)/256) for the streaming kernel
#define NPCH 16                 // p-chunks per row
#define PCH 3125                // NP/NPCH: preds per argmax block

__device__ __forceinline__ void opaque(float& x) { asm volatile("" : "+v"(x)); }
__device__ __forceinline__ unsigned long long umax64(unsigned long long a, unsigned long long b) {
    return a > b ? a : b;
}

// ---------------------------------------------------------------------------
// Kernel B: row-oriented argmax partials, RECOMPUTING iou from pred (6.4 MB read).
// Grid (NPCH, 8 g-groups, NB). Each block: 8 g-rows x PCH preds.
// part[row = b*NG+g][chunk] = (iou_bits<<32) | (0xFFFFFFFF - p)
// u64 max == argmax with first-occurrence tie-break.
// NOTE: accumulators ka[8] are statically indexed ONLY (rule #20 — Round 8's
// pointer-array version forced them to scratch, ~3x kernel slowdown).
__global__ __launch_bounds__(256) void argmax_part(
    const float* __restrict__ pred,
    const float* __restrict__ gt,
    unsigned long long* __restrict__ part)
{
    __shared__ float s_gx0[8], s_gy0[8], s_gx1[8], s_gy1[8], s_ga[8];
    const int b  = blockIdx.z;
    const int gg = blockIdx.y;
    const int p0 = blockIdx.x * PCH;
    const int tid = threadIdx.x;

    if (tid < 8) {
        const float4 gb = reinterpret_cast<const float4*>(gt)[b * NG + gg * 8 + tid];
        float hw = 0.5f * gb.z, hh = 0.5f * gb.w;   // exact, FMA-safe
        float x0 = gb.x - hw, y0 = gb.y - hh;
        float x1 = gb.x + hw, y1 = gb.y + hh;
        float ga = (x1 - x0) * (y1 - y0);
        opaque(ga);
        s_gx0[tid] = x0; s_gy0[tid] = y0;
        s_gx1[tid] = x1; s_gy1[tid] = y1;
        s_ga[tid]  = ga;
    }
    __syncthreads();

    unsigned long long ka[8] = {0,0,0,0,0,0,0,0};

    for (int i = tid; i < PCH; i += 256) {
        const int p = p0 + i;
        const float4 pb = reinterpret_cast<const float4*>(pred)[(size_t)b * NP + p];
        float hw = 0.5f * pb.z, hh = 0.5f * pb.w;
        const float px0 = pb.x - hw, py0 = pb.y - hh;
        const float px1 = pb.x + hw, py1 = pb.y + hh;
        float pa = (px1 - px0) * (py1 - py0);
        opaque(pa);

        const unsigned long long ip = (unsigned long long)(0xFFFFFFFFu - (unsigned int)p);
        #pragma unroll
        for (int j = 0; j < 8; ++j) {
            // identical expression structure to the streaming kernel -> bitwise-equal iou
            float w = fmaxf(fminf(s_gx1[j], px1) - fmaxf(s_gx0[j], px0), 0.0f);
            float h = fmaxf(fminf(s_gy1[j], py1) - fmaxf(s_gy0[j], py0), 0.0f);
            float inter = w * h;
            opaque(inter);                           // numpy op order: (ga+pa)-inter
            float iou = inter / ((s_ga[j] + pa) - inter);  // IEEE div
            unsigned long long key = ((unsigned long long)__float_as_uint(iou) << 32) | ip;
            ka[j] = umax64(ka[j], key);              // static index (full unroll)
        }
    }

    // block reduction: butterfly within wave, LDS across the 4 waves
    __shared__ unsigned long long s_part[8][4];
    const int lane = tid & 63;
    const int wv = tid >> 6;
    #pragma unroll
    for (int j = 0; j < 8; ++j) {
        unsigned long long k = ka[j];
        #pragma unroll
        for (int s = 1; s < 64; s <<= 1)
            k = umax64(k, __shfl_xor(k, s, 64));
        if (lane == 0) s_part[j][wv] = k;
    }
    __syncthreads();

    if (tid < 8) {
        unsigned long long r = umax64(umax64(s_part[tid][0], s_part[tid][1]),
                                      umax64(s_part[tid][2], s_part[tid][3]));
        part[((size_t)b * NG + (size_t)(gg * 8 + tid)) * NPCH + blockIdx.x] = r;
    }
}

// ---------------------------------------------------------------------------
// Kernel A: pure streaming — iou, pos (threshold | onehot), neg. One pass.
template<bool USE_AM>
__global__ __launch_bounds__(256) void iou_main(
    const float* __restrict__ pred,
    const float* __restrict__ gt,
    float* __restrict__ out_iou,
    float* __restrict__ out_pos,
    float* __restrict__ out_neg,
    const unsigned long long* __restrict__ part)
{
    __shared__ float s_gx0[NG], s_gy0[NG], s_gx1[NG], s_gy1[NG], s_ga[NG];
    __shared__ unsigned int s_am[NG];
    const int b = blockIdx.y;
    const int tid = threadIdx.x;

    if (tid < NG) {
        const float4 gb = reinterpret_cast<const float4*>(gt)[b * NG + tid];
        float hw = 0.5f * gb.z, hh = 0.5f * gb.w;   // exact, FMA-safe
        float x0 = gb.x - hw, y0 = gb.y - hh;
        float x1 = gb.x + hw, y1 = gb.y + hh;
        float ga = (x1 - x0) * (y1 - y0);
        opaque(ga);                                  // block FMA contraction into sums
        s_gx0[tid] = x0; s_gy0[tid] = y0;
        s_gx1[tid] = x1; s_gy1[tid] = y1;
        s_ga[tid]  = ga;
        if (USE_AM) {
            const unsigned long long* pr = part + ((size_t)b * NG + tid) * NPCH;
            unsigned long long r = pr[0];
            #pragma unroll
            for (int c = 1; c < NPCH; ++c) r = umax64(r, pr[c]);
            s_am[tid] = 0xFFFFFFFFu - (unsigned int)(r & 0xFFFFFFFFull);
        }
    }
    __syncthreads();

    const int p = 2 * (blockIdx.x * 256 + tid);
    if (p >= NP) return;                             // no barriers after this

    const float4 pb0 = reinterpret_cast<const float4*>(pred)[(size_t)b * NP + p];
    const float4 pb1 = reinterpret_cast<const float4*>(pred)[(size_t)b * NP + p + 1];

    float hw0 = 0.5f * pb0.z, hh0 = 0.5f * pb0.w;
    const float ax0 = pb0.x - hw0, ay0 = pb0.y - hh0;
    const float ax1 = pb0.x + hw0, ay1 = pb0.y + hh0;
    float pa0 = (ax1 - ax0) * (ay1 - ay0);
    opaque(pa0);

    float hw1 = 0.5f * pb1.z, hh1 = 0.5f * pb1.w;
    const float bx0 = pb1.x - hw1, by0 = pb1.y - hh1;
    const float bx1 = pb1.x + hw1, by1 = pb1.y + hh1;
    float pa1 = (bx1 - bx0) * (by1 - by0);
    opaque(pa1);

    float maxv0 = 0.0f, maxv1 = 0.0f;
    const size_t base = (size_t)b * NG * NP + (size_t)p;
    const unsigned int up = (unsigned int)p;

    #pragma unroll 8
    for (int g = 0; g < NG; ++g) {
        const float gx0 = s_gx0[g], gy0 = s_gy0[g];
        const float gx1 = s_gx1[g], gy1 = s_gy1[g];
        const float ga  = s_ga[g];

        float w0 = fmaxf(fminf(gx1, ax1) - fmaxf(gx0, ax0), 0.0f);
        float h0 = fmaxf(fminf(gy1, ay1) - fmaxf(gy0, ay0), 0.0f);
        float inter0 = w0 * h0;
        opaque(inter0);                              // numpy op order: (ga+pa)-inter
        float iou0 = inter0 / ((ga + pa0) - inter0); // IEEE div

        float w1 = fmaxf(fminf(gx1, bx1) - fmaxf(gx0, bx0), 0.0f);
        float h1 = fmaxf(fminf(gy1, by1) - fmaxf(gy0, by0), 0.0f);
        float inter1 = w1 * h1;
        opaque(inter1);
        float iou1 = inter1 / ((ga + pa1) - inter1);

        float2 vi; vi.x = iou0; vi.y = iou1;
        *reinterpret_cast<float2*>(out_iou + base + (size_t)g * NP) = vi;

        float2 vp;
        if (USE_AM) {
            const unsigned int am = s_am[g];
            vp.x = (iou0 > 0.7f || am == up)      ? 1.0f : 0.0f;
            vp.y = (iou1 > 0.7f || am == up + 1u) ? 1.0f : 0.0f;
        } else {
            vp.x = (iou0 > 0.7f) ? 1.0f : 0.0f;
            vp.y = (iou1 > 0.7f) ? 1.0f : 0.0f;
        }
        *reinterpret_cast<float2*>(out_pos + base + (size_t)g * NP) = vp;

        maxv0 = fmaxf(maxv0, iou0);
        maxv1 = fmaxf(maxv1, iou1);
    }

    float2 vn; vn.x = (maxv0 < 0.3f) ? 1.0f : 0.0f;
               vn.y = (maxv1 < 0.3f) ? 1.0f : 0.0f;
    *reinterpret_cast<float2*>(out_neg + (size_t)b * NP + p) = vn;
}

// Fallback (ws too small): re-scan the iou row for argmax.
__global__ __launch_bounds__(256) void argmax_scan(
    const float* __restrict__ out_iou,
    float* __restrict__ out_pos)
{
    const int row = blockIdx.x;
    const float4* r4 = reinterpret_cast<const float4*>(out_iou + (size_t)row * NP);

    float bv = -1.0f;
    int   bi = 0x7fffffff;
    for (int c = threadIdx.x; c < NP / 4; c += 256) {
        float4 v = r4[c];
        int p = 4 * c;
        if (v.x > bv) { bv = v.x; bi = p; }
        if (v.y > bv) { bv = v.y; bi = p + 1; }
        if (v.z > bv) { bv = v.z; bi = p + 2; }
        if (v.w > bv) { bv = v.w; bi = p + 3; }
    }
    #pragma unroll
    for (int s = 1; s < 64; s <<= 1) {
        float ov = __shfl_xor(bv, s, 64);
        int   oi = __shfl_xor(bi, s, 64);
        if (ov > bv || (ov == bv && oi < bi)) { bv = ov; bi = oi; }
    }
    __shared__ float sv[4];
    __shared__ int   si[4];
    const int wid = threadIdx.x >> 6;
    if ((threadIdx.x & 63) == 0) { sv[wid] = bv; si[wid] = bi; }
    __syncthreads();
    if (threadIdx.x == 0) {
        for (int w = 1; w < 4; ++w)
            if (sv[w] > bv || (sv[w] == bv && si[w] < bi)) { bv = sv[w]; bi = si[w]; }
        out_pos[(size_t)row * NP + bi] = 1.0f;
    }
}

extern "C" void kernel_launch(void* const* d_in, const int* in_sizes, int n_in,
                              void* d_out, int out_size, void* d_ws, size_t ws_size,
                              hipStream_t stream) {
    const float* pred = (const float*)d_in[0];
    const float* gt   = (const float*)d_in[1];
    float* out_iou = (float*)d_out;
    float* out_pos = out_iou + (size_t)NB * NG * NP;
    float* out_neg = out_pos + (size_t)NB * NG * NP;

    const size_t part_bytes = (size_t)NB * NG * NPCH * sizeof(unsigned long long); // 64 KB
    dim3 gridA(NBLK, NB);

    if (ws_size >= part_bytes) {
        unsigned long long* part = (unsigned long long*)d_ws;
        argmax_part<<<dim3(NPCH, NG / 8, NB), dim3(256), 0, stream>>>(pred, gt, part);
        iou_main<true><<<gridA, dim3(256), 0, stream>>>(pred, gt, out_iou, out_pos, out_neg, part);
    } else {
        iou_main<false><<<gridA, dim3(256), 0, stream>>>(pred, gt, out_iou, out_pos, out_neg, nullptr);
        argmax_scan<<<dim3(NB * NG), dim3(256), 0, stream>>>(out_iou, out_pos);
    }
}